// Round 1
// baseline (694.653 us; speedup 1.0000x reference)
//
#include <hip/hip_runtime.h>

// BarycentricPooling closed form.
//
// The reference's final update computes g from the final f and the same C used
// in log_pi. Hence for every graph n:
//   LSE_s(log_pi[n,:,k]) = lb_k + g_k/eps + LSE_s(la + (f-C)/eps) = lb_k
// because g_k = -eps * LSE_s(la + (f-C)/eps) exactly (the g-half-update
// enforces the transport plan's second marginal = b). So
//   hist[n,:] == softmax(log_prior)  exactly, for any C, any iteration count.
// Segment-mean of identical rows is the row; the empty-graph fallback is the
// same softmax. Output is softmax(log_codebook_prior) broadcast over B rows.

__global__ void BarycentricPooling_22660247453772_kernel(
    const float* __restrict__ log_prior,  // [K]
    float* __restrict__ out,              // [B*K] flat
    int K, int total) {
    int i = blockIdx.x * blockDim.x + threadIdx.x;
    if (i >= total) return;
    int k = i % K;

    // softmax over the K prior entries (tiny: K=64, L1-broadcast reads)
    float m = -3.402823466e38f;
    for (int j = 0; j < K; ++j) m = fmaxf(m, log_prior[j]);
    float s = 0.0f;
    for (int j = 0; j < K; ++j) s += expf(log_prior[j] - m);
    out[i] = expf(log_prior[k] - m) / s;
}

extern "C" void kernel_launch(void* const* d_in, const int* in_sizes, int n_in,
                              void* d_out, int out_size, void* d_ws, size_t ws_size,
                              hipStream_t stream) {
    // inputs (setup_inputs order):
    //   d_in[0] node_distributions [N,S,D] f32  (mathematically dead)
    //   d_in[1] batch_idx          [N]     i32  (mathematically dead)
    //   d_in[2] codebook           [K,D]   f32  (mathematically dead)
    //   d_in[3] log_codebook_prior [K]     f32
    const float* log_prior = (const float*)d_in[3];
    float* out = (float*)d_out;

    int K = in_sizes[3];          // 64
    int total = out_size;         // B*K = 256*64 = 16384

    int threads = 256;
    int blocks = (total + threads - 1) / threads;
    hipLaunchKernelGGL(BarycentricPooling_22660247453772_kernel,
                       dim3(blocks), dim3(threads), 0, stream,
                       log_prior, out, K, total);
}